// Round 7
// baseline (394.980 us; speedup 1.0000x reference)
//
#include <hip/hip_runtime.h>
#include <hip/hip_bf16.h>

// AgriMatcher: normalize(+bf16 hi/lo split, fused v0-init) -> MFMA cosine-sim GEMM ->
// fused fp32 log-Sinkhorn(5) (u+v in one matrix pass per iteration) ->
// per-row top-8 (u64-key selection, exact ordering) + entropy ->
// banded 7x7 local variance geometric score -> softmax warp.
// B=2, N=4096=64x64, C=128, K=8, TEMP=0.05, RADIUS=3.
//
// R2: cg-coop Sinkhorn spilled (VGPR=64, scratch) -> 910us. Reverted.
// R4: divergent hierarchical top-8 LOST (81->88us): winner-lane rescan broke ILP.
// R5: branchless sorted-groups finalize WON (~-15us); nt hints on part LOST (+14). Reverted nt.
// R7: serpentine sim passes. Evidence: finalize FETCH=66MB of 134MB (50% L3 hit) --
//     same-direction streaming evicts the head right before the next pass needs it.
//     Alternate pass direction via linear-block-id flip (bit-identical work per block;
//     gemm writes tail last -> pass0 reversed; pass4 reversed ends at b0row0 -> finalize fwd).

#define NB 2
#define NN 4096
#define NC 128
#define NK 8
#define VST 4104   // padded stride for u/v vectors

constexpr float INV_TEMP   = 20.0f;
constexpr float NORM_CONST = -9.010913347279289f;    // -log(8192)
constexpr float LOG_DUST   = -0.6931471805599453f;   // log(4096)-log(8192)

typedef __attribute__((ext_vector_type(8))) short bf16x8;
typedef __attribute__((ext_vector_type(4))) float f32x4;

// ---------------- 1. L2 normalize rows + bf16 hi/lo split (+ v0 zero-fill) ----------------
__global__ void norm_split(const float* __restrict__ fa, const float* __restrict__ fb,
                           __hip_bfloat16* __restrict__ Ah, __hip_bfloat16* __restrict__ Al,
                           __hip_bfloat16* __restrict__ Bh, __hip_bfloat16* __restrict__ Bl,
                           float* __restrict__ v0) {
  int row = blockIdx.x;
  int t = threadIdx.x;
  // fused init: first 129 blocks zero v0 (read only 2 kernels later)
  if (row < (NB * VST + 63) / 64) {
    int i = row * 64 + t;
    if (i < NB * VST) v0[i] = 0.0f;
  }
  bool isB = row >= NB * NN;
  int base = isB ? row - NB * NN : row;
  const float* src = (isB ? fb : fa) + (size_t)base * NC;
  __hip_bfloat16* dh = (isB ? Bh : Ah) + (size_t)base * NC;
  __hip_bfloat16* dl = (isB ? Bl : Al) + (size_t)base * NC;
  float x0 = src[t], x1 = src[t + 64];
  float ss = x0 * x0 + x1 * x1;
  #pragma unroll
  for (int o = 32; o; o >>= 1) ss += __shfl_xor(ss, o);
  float nrm = fmaxf(sqrtf(ss), 1e-12f);
  float y0 = x0 / nrm, y1 = x1 / nrm;
  __hip_bfloat16 h0 = __float2bfloat16(y0);
  __hip_bfloat16 h1 = __float2bfloat16(y1);
  dh[t] = h0;      dl[t] = __float2bfloat16(y0 - __bfloat162float(h0));
  dh[t + 64] = h1; dl[t + 64] = __float2bfloat16(y1 - __bfloat162float(h1));
}

// ---------------- 2. MFMA GEMM: sim = A.B^T via bf16 hi/lo split ----------------
__launch_bounds__(256, 2)
__global__ void gemm_mfma(const __hip_bfloat16* __restrict__ Ah, const __hip_bfloat16* __restrict__ Al,
                          const __hip_bfloat16* __restrict__ Bh, const __hip_bfloat16* __restrict__ Bl,
                          float* __restrict__ sim) {
  __shared__ __hip_bfloat16 sAh[128 * 64], sAl[128 * 64];
  __shared__ __hip_bfloat16 sBh[128 * 64], sBl[128 * 64];
  const int b = blockIdx.z, m0 = blockIdx.y * 128, n0 = blockIdx.x * 128;
  const int t = threadIdx.x;
  const int wid = t >> 6, l = t & 63, q = l >> 4, lm = l & 15;
  const int wm = (wid >> 1) * 64, wn = (wid & 1) * 64;
  f32x4 acc[4][4] = {};
  const __hip_bfloat16* gAh = Ah + ((size_t)b * NN + m0) * NC;
  const __hip_bfloat16* gAl = Al + ((size_t)b * NN + m0) * NC;
  const __hip_bfloat16* gBh = Bh + ((size_t)b * NN + n0) * NC;
  const __hip_bfloat16* gBl = Bl + ((size_t)b * NN + n0) * NC;

  for (int koff = 0; koff < NC; koff += 64) {
    #pragma unroll
    for (int ii = 0; ii < 4; ii++) {
      int id = t + 256 * ii;
      int row = id >> 3, cc = id & 7;
      int gofs = row * NC + koff + cc * 8;
      int lofs = row * 64 + ((cc ^ (row & 7)) << 3);
      *(float4*)&sAh[lofs] = *(const float4*)(gAh + gofs);
      *(float4*)&sAl[lofs] = *(const float4*)(gAl + gofs);
      *(float4*)&sBh[lofs] = *(const float4*)(gBh + gofs);
      *(float4*)&sBl[lofs] = *(const float4*)(gBl + gofs);
    }
    __syncthreads();
    #pragma unroll
    for (int ks = 0; ks < 2; ks++) {
      int cc = ks * 4 + q;
      bf16x8 a_h[4], a_l[4], b_h[4], b_l[4];
      #pragma unroll
      for (int i = 0; i < 4; i++) {
        int r = wm + i * 16 + lm;
        int ro = r * 64 + ((cc ^ (r & 7)) << 3);
        a_h[i] = *(const bf16x8*)&sAh[ro];
        a_l[i] = *(const bf16x8*)&sAl[ro];
        int n = wn + i * 16 + lm;
        int no = n * 64 + ((cc ^ (n & 7)) << 3);
        b_h[i] = *(const bf16x8*)&sBh[no];
        b_l[i] = *(const bf16x8*)&sBl[no];
      }
      #pragma unroll
      for (int i = 0; i < 4; i++) {
        #pragma unroll
        for (int j = 0; j < 4; j++) {
          acc[i][j] = __builtin_amdgcn_mfma_f32_16x16x32_bf16(a_h[i], b_h[j], acc[i][j], 0, 0, 0);
          acc[i][j] = __builtin_amdgcn_mfma_f32_16x16x32_bf16(a_h[i], b_l[j], acc[i][j], 0, 0, 0);
          acc[i][j] = __builtin_amdgcn_mfma_f32_16x16x32_bf16(a_l[i], b_h[j], acc[i][j], 0, 0, 0);
        }
      }
    }
    __syncthreads();
  }
  // C/D layout (m89-verified): col = lane&15, row = (lane>>4)*4 + reg
  float* ob = sim + (size_t)b * NN * NN;
  #pragma unroll
  for (int i = 0; i < 4; i++) {
    #pragma unroll
    for (int j = 0; j < 4; j++) {
      int col = n0 + wn + j * 16 + lm;
      #pragma unroll
      for (int reg = 0; reg < 4; reg++) {
        int r = m0 + wm + i * 16 + q * 4 + reg;
        ob[(size_t)r * NN + col] = acc[i][j][reg];
      }
    }
  }
}

// ---------------- 3a. fused Sinkhorn pass: u for 8 rows + column partials ----------------
// rev flips the linear block id (batch+row together) so alternating passes stream sim
// in opposite directions (LRU-friendly). Work per (b,blk) is bit-identical either way.
__launch_bounds__(512, 4)
__global__ void sink_fused(const float* __restrict__ sim, const float* __restrict__ vin,
                           float* __restrict__ u, float* __restrict__ part, int rev) {
  int L = blockIdx.y * 512 + blockIdx.x;
  if (rev) L = NB * 512 - 1 - L;
  int b = L >> 9, blk = L & 511;
  int t = threadIdx.x;
  int r0 = blk * 8, c0 = t * 8;
  const float* vb = vin + b * VST;
  const float* srow0 = sim + ((size_t)b * NN + r0) * NN + c0;

  float4 va0 = *(const float4*)(vb + c0);
  float4 va1 = *(const float4*)(vb + c0 + 4);
  float vm[8] = {va0.x - 30.0f, va0.y - 30.0f, va0.z - 30.0f, va0.w - 30.0f,
                 va1.x - 30.0f, va1.y - 30.0f, va1.z - 30.0f, va1.w - 30.0f};
  float E[8][8];
  float rp[8];
  #pragma unroll
  for (int r = 0; r < 8; r++) {
    const float4* sp = (const float4*)(srow0 + (size_t)r * NN);
    float4 s0 = sp[0], s1 = sp[1];
    E[r][0] = __expf(fmaf(s0.x, INV_TEMP, vm[0]));
    E[r][1] = __expf(fmaf(s0.y, INV_TEMP, vm[1]));
    E[r][2] = __expf(fmaf(s0.z, INV_TEMP, vm[2]));
    E[r][3] = __expf(fmaf(s0.w, INV_TEMP, vm[3]));
    E[r][4] = __expf(fmaf(s1.x, INV_TEMP, vm[4]));
    E[r][5] = __expf(fmaf(s1.y, INV_TEMP, vm[5]));
    E[r][6] = __expf(fmaf(s1.z, INV_TEMP, vm[6]));
    E[r][7] = __expf(fmaf(s1.w, INV_TEMP, vm[7]));
    rp[r] = ((E[r][0] + E[r][1]) + (E[r][2] + E[r][3]))
          + ((E[r][4] + E[r][5]) + (E[r][6] + E[r][7]));
  }
  #pragma unroll
  for (int r = 0; r < 8; r++) {
    #pragma unroll
    for (int o = 1; o < 64; o <<= 1) rp[r] += __shfl_xor(rp[r], o);
  }
  __shared__ float ws[8][8];   // [wave][row]
  __shared__ float eus[8];
  int w = t >> 6;
  if ((t & 63) == 0) {
    #pragma unroll
    for (int r = 0; r < 8; r++) ws[w][r] = rp[r];
  }
  __syncthreads();
  if (t < 8) {
    float S = 0.0f;
    #pragma unroll
    for (int ww = 0; ww < 8; ww++) S += ws[ww][t];
    S += __expf(vb[NN] - 30.0f);               // dustbin column term
    float ur = NORM_CONST - 30.0f - __logf(S);
    u[b * VST + r0 + t] = ur;
    eus[t] = __expf(ur);
  }
  __syncthreads();
  float eu[8];
  #pragma unroll
  for (int r = 0; r < 8; r++) eu[r] = eus[r];
  float outp[8];
  #pragma unroll
  for (int c = 0; c < 8; c++) {
    float acc = E[0][c] * eu[0];
    #pragma unroll
    for (int r = 1; r < 8; r++) acc = fmaf(E[r][c], eu[r], acc);
    outp[c] = acc * __expf(-30.0f - vm[c]);    // * exp(-v_c)
  }
  float* pp = part + ((size_t)b * 512 + blk) * NN + c0;
  *(float4*)pp       = make_float4(outp[0], outp[1], outp[2], outp[3]);
  *(float4*)(pp + 4) = make_float4(outp[4], outp[5], outp[6], outp[7]);
}

// ---------------- 3b. stage2: reduce column partials -> v; dustbins ----------------
__launch_bounds__(256)
__global__ void sink_stage2(const float* __restrict__ part, const float* __restrict__ vin,
                            const float* __restrict__ u, float* __restrict__ vout) {
  int b = blockIdx.y, t = threadIdx.x;
  const float* vb = vin + b * VST;
  // u_dust = LOG_DUST - 30 - log( sum_c exp(v_c-30) + exp(v_dust-30) )
  float sv = 0.0f;
  #pragma unroll
  for (int i = 0; i < 16; i++) sv += __expf(vb[t + (i << 8)] - 30.0f);
  #pragma unroll
  for (int o = 1; o < 64; o <<= 1) sv += __shfl_xor(sv, o);
  __shared__ float sa[4];
  if ((t & 63) == 0) sa[t >> 6] = sv;
  __syncthreads();
  float S_v = sa[0] + sa[1] + sa[2] + sa[3] + __expf(vb[NN] - 30.0f);
  float eud = __expf(LOG_DUST - 60.0f - __logf(S_v));  // exp(u_dust - 30)

  int c = t & 31, h = t >> 5;
  int col = blockIdx.x * 32 + c;
  const float* pb = part + (size_t)b * 512 * NN + col;
  float acc = 0.0f;
  #pragma unroll 4
  for (int j = 0; j < 64; j++) acc += pb[(size_t)(h * 64 + j) * NN];
  __shared__ float red[256];
  red[t] = acc;
  __syncthreads();
  if (h == 0) {
    #pragma unroll
    for (int g = 1; g < 8; g++) acc += red[g * 32 + c];
    vout[b * VST + col] = NORM_CONST - 30.0f - __logf(acc + eud);
  }
  if (blockIdx.x == 0) {
    const float* ub = u + b * VST;
    float su = 0.0f;
    #pragma unroll
    for (int i = 0; i < 16; i++) su += __expf(ub[t + (i << 8)] - 30.0f);
    #pragma unroll
    for (int o = 1; o < 64; o <<= 1) su += __shfl_xor(su, o);
    __shared__ float sb[4];
    if ((t & 63) == 0) sb[t >> 6] = su;
    __syncthreads();
    if (t == 0)
      vout[b * VST + NN] = LOG_DUST - 30.0f - __logf(sb[0] + sb[1] + sb[2] + sb[3] + eud);
  }
}

// ---------------- 4. finalize: top-8 via u64 keys (exact ordering), entropy ----------------
// R5: branchless sorted-groups selection. Each lane pre-sorts its 4 groups of 4 keys
// (5-CE network, pure ILP). Per round: global max = max of 4 group heads (3 u64-max),
// butterfly, then a uniform shift-register pop in the winner's group. Keys are unique
// (index in low bits) -> emitted sequence identical to the flat 16-key scan.
__launch_bounds__(256)
__global__ void finalize_rows(const float* __restrict__ sim, const float* __restrict__ u,
                              const float* __restrict__ v, float* __restrict__ tkv,
                              int* __restrict__ tki, float* __restrict__ ent) {
  int m = blockIdx.x, b = blockIdx.y, t = threadIdx.x;
  const float4* srow = (const float4*)(sim + ((size_t)b * NN + m) * NN);
  const float4* v4 = (const float4*)(v + b * VST);
  float um = u[b * VST + m];
  unsigned long long key[16];
  float T1 = 0.0f, T2 = 0.0f;
  #pragma unroll
  for (int i = 0; i < 4; i++) {
    int idx = t + (i << 8);
    float4 s = srow[idx], vv = v4[idx];
    unsigned n0 = 4u * (unsigned)idx;
    float z, e;
    unsigned zb, k;
    z = fmaf(s.x, INV_TEMP, vv.x + um); e = __expf(z); T1 += e; T2 = fmaf(e, z, T2);
    zb = __float_as_uint(z); k = (zb & 0x80000000u) ? ~zb : (zb | 0x80000000u);
    key[4 * i + 0] = ((unsigned long long)k << 32) | (unsigned)(~n0);
    z = fmaf(s.y, INV_TEMP, vv.y + um); e = __expf(z); T1 += e; T2 = fmaf(e, z, T2);
    zb = __float_as_uint(z); k = (zb & 0x80000000u) ? ~zb : (zb | 0x80000000u);
    key[4 * i + 1] = ((unsigned long long)k << 32) | (unsigned)(~(n0 + 1));
    z = fmaf(s.z, INV_TEMP, vv.z + um); e = __expf(z); T1 += e; T2 = fmaf(e, z, T2);
    zb = __float_as_uint(z); k = (zb & 0x80000000u) ? ~zb : (zb | 0x80000000u);
    key[4 * i + 2] = ((unsigned long long)k << 32) | (unsigned)(~(n0 + 2));
    z = fmaf(s.w, INV_TEMP, vv.w + um); e = __expf(z); T1 += e; T2 = fmaf(e, z, T2);
    zb = __float_as_uint(z); k = (zb & 0x80000000u) ? ~zb : (zb | 0x80000000u);
    key[4 * i + 3] = ((unsigned long long)k << 32) | (unsigned)(~(n0 + 3));
  }
  #pragma unroll
  for (int o = 1; o < 64; o <<= 1) { T1 += __shfl_xor(T1, o); T2 += __shfl_xor(T2, o); }

  // pre-sort each group of 4 descending (sorting network [(0,1)(2,3)(0,2)(1,3)(1,2)])
  #pragma unroll
  for (int gi = 0; gi < 4; gi++) {
    unsigned long long k0 = key[4 * gi], k1 = key[4 * gi + 1];
    unsigned long long k2 = key[4 * gi + 2], k3 = key[4 * gi + 3];
    unsigned long long hi, lo;
    hi = k0 > k1 ? k0 : k1; lo = k0 > k1 ? k1 : k0; k0 = hi; k1 = lo;
    hi = k2 > k3 ? k2 : k3; lo = k2 > k3 ? k3 : k2; k2 = hi; k3 = lo;
    hi = k0 > k2 ? k0 : k2; lo = k0 > k2 ? k2 : k0; k0 = hi; k2 = lo;
    hi = k1 > k3 ? k1 : k3; lo = k1 > k3 ? k3 : k1; k1 = hi; k3 = lo;
    hi = k1 > k2 ? k1 : k2; lo = k1 > k2 ? k2 : k1; k1 = hi; k2 = lo;
    key[4 * gi] = k0; key[4 * gi + 1] = k1; key[4 * gi + 2] = k2; key[4 * gi + 3] = k3;
  }

  unsigned long long wv[8];
  #pragma unroll
  for (int r = 0; r < 8; r++) {
    unsigned long long m01 = key[0] > key[4] ? key[0] : key[4];
    unsigned long long m23 = key[8] > key[12] ? key[8] : key[12];
    unsigned long long mx = m01 > m23 ? m01 : m23;
    #pragma unroll
    for (int o = 1; o < 64; o <<= 1) {
      unsigned long long om = __shfl_xor(mx, o);
      mx = (om > mx) ? om : mx;
    }
    wv[r] = mx;
    // branchless pop: only the winner's group head can equal mx (keys unique)
    #pragma unroll
    for (int gi = 0; gi < 4; gi++) {
      bool c = (key[4 * gi] == mx);
      key[4 * gi]     = c ? key[4 * gi + 1] : key[4 * gi];
      key[4 * gi + 1] = c ? key[4 * gi + 2] : key[4 * gi + 1];
      key[4 * gi + 2] = c ? key[4 * gi + 3] : key[4 * gi + 2];
      key[4 * gi + 3] = c ? 0ull            : key[4 * gi + 3];
    }
  }

  __shared__ unsigned long long lv[4][8];
  __shared__ unsigned long long fv[8];
  __shared__ float sT1[4], sT2[4];
  int wid = t >> 6;
  if ((t & 63) == 0) {
    sT1[wid] = T1; sT2[wid] = T2;
    #pragma unroll
    for (int j = 0; j < 8; j++) lv[wid][j] = wv[j];
  }
  __syncthreads();
  if (t == 0) {
    int p[4] = {0, 0, 0, 0};
    for (int k2 = 0; k2 < 8; k2++) {
      unsigned long long best = 0ull; int bw = 0;
      #pragma unroll
      for (int w = 0; w < 4; w++) {
        if (p[w] < 8 && lv[w][p[w]] > best) { best = lv[w][p[w]]; bw = w; }
      }
      fv[k2] = best; p[bw]++;
    }
  }
  __syncthreads();
  size_t ro = ((size_t)b * NN + m) * NK;
  if (t < 8) {
    unsigned long long kk = fv[t];
    unsigned kh = (unsigned)(kk >> 32);
    unsigned zb = (kh & 0x80000000u) ? (kh & 0x7FFFFFFFu) : ~kh;
    tkv[ro + t] = __expf(__uint_as_float(zb));
    tki[ro + t] = (int)(~(unsigned)kk);
  }
  if (t == 0) {
    float T1t = sT1[0] + sT1[1] + sT1[2] + sT1[3];
    float T2t = sT2[0] + sT2[1] + sT2[2] + sT2[3];
    float denom = T1t + 1e-8f;
    float ld = __logf(denom);
    ent[b * NN + m] = (T1t * ld - T2t) / denom;
  }
}

// ---------------- 5. geometric score: banded 7x7 local variance ----------------
__launch_bounds__(256)
__global__ void geo_kernel(const int* __restrict__ tki, const float* __restrict__ posA,
                           const float* __restrict__ posB, float* __restrict__ geo) {
  int k = blockIdx.x, band = blockIdx.y, b = blockIdx.z, t = threadIdx.x;
  int r0 = band * 8, rlo = r0 - 3;
  __shared__ float s1[14 * 64], s2[14 * 64], h1[14 * 64], h2[14 * 64];
  const float* pA = posA + (size_t)b * NN * 2;
  const float* pB = posB + (size_t)b * NN * 2;
  const int* idx = tki + (size_t)b * NN * NK + k;
  for (int e = t; e < 14 * 64; e += 256) {
    int rr = rlo + (e >> 6), w = e & 63;
    float v1 = 0.0f, v2 = 0.0f;
    if (rr >= 0 && rr < 64) {
      int n = rr * 64 + w;
      int j = idx[(size_t)n * NK];
      float dx = pB[(size_t)j * 2]     - pA[(size_t)n * 2];
      float dy = pB[(size_t)j * 2 + 1] - pA[(size_t)n * 2 + 1];
      v1 = dx + dy;
      v2 = dx * dx + dy * dy;
    }
    s1[e] = v1; s2[e] = v2;
  }
  __syncthreads();
  for (int e = t; e < 14 * 64; e += 256) {
    int w = e & 63, base = e - w;
    float a1 = 0.0f, a2 = 0.0f;
    for (int dw = -3; dw <= 3; dw++) {
      int ww = w + dw;
      if (ww >= 0 && ww < 64) { a1 += s1[base + ww]; a2 += s2[base + ww]; }
    }
    h1[e] = a1; h2[e] = a2;
  }
  __syncthreads();
  for (int o = t; o < 8 * 64; o += 256) {
    int lr = (o >> 6) + 3, w = o & 63;
    int e = lr * 64 + w;
    float b1 = 0.0f, b2 = 0.0f;
    #pragma unroll
    for (int dh = -3; dh <= 3; dh++) { b1 += h1[e + dh * 64]; b2 += h2[e + dh * 64]; }
    float mean = b1 * (1.0f / 98.0f);
    float var = (b2 - b1 * mean) * (1.0f / 97.0f);
    int n = (r0 + (o >> 6)) * 64 + w;
    geo[((size_t)b * NN + n) * NK + k] = 1.0f / (1.0f + var * 100.0f);
  }
}

// ---------------- 6. combine: softmax over K, weighted warp ----------------
__launch_bounds__(256)
__global__ void combine_kernel(const float* __restrict__ tkv, const float* __restrict__ geo,
                               const int* __restrict__ tki, const float* __restrict__ posB,
                               float* __restrict__ warp) {
  int id = blockIdx.x * 256 + threadIdx.x;
  int b = id / NN;
  const float* vals = tkv + (size_t)id * NK;
  const float* g    = geo + (size_t)id * NK;
  const int*   ix   = tki + (size_t)id * NK;
  const float* pB   = posB + (size_t)b * NN * 2;
  float l[8], mx = -3.0e38f;
  #pragma unroll
  for (int j = 0; j < 8; j++) {
    l[j] = (vals[j] + 1.5f * g[j]) * INV_TEMP;
    mx = fmaxf(mx, l[j]);
  }
  float sw = 0.0f, wx = 0.0f, wy = 0.0f;
  #pragma unroll
  for (int j = 0; j < 8; j++) {
    float w = __expf(l[j] - mx);
    int jj = ix[j];
    sw += w;
    wx = fmaf(w, pB[(size_t)jj * 2], wx);
    wy = fmaf(w, pB[(size_t)jj * 2 + 1], wy);
  }
  warp[(size_t)id * 2]     = wx / sw;
  warp[(size_t)id * 2 + 1] = wy / sw;
}

extern "C" void kernel_launch(void* const* d_in, const int* in_sizes, int n_in,
                              void* d_out, int out_size, void* d_ws, size_t ws_size,
                              hipStream_t stream) {
  const float* fA = (const float*)d_in[0];
  const float* fB = (const float*)d_in[1];
  const float* pA = (const float*)d_in[2];
  const float* pB = (const float*)d_in[3];

  float* out  = (float*)d_out;
  float* warp = out;                       // [B,N,2]
  float* ent  = out + (size_t)NB * NN * 2; // [B,N]
  float* sim  = ent + (size_t)NB * NN;     // [B,N,N] raw_sim (also Sinkhorn cost)

  size_t off = 0;
  auto take = [&](size_t bytes) {
    void* p = (char*)d_ws + off;
    off = (off + bytes + 255) & ~(size_t)255;
    return p;
  };
  __hip_bfloat16* Ah = (__hip_bfloat16*)take((size_t)NB * NN * NC * 2);
  __hip_bfloat16* Al = (__hip_bfloat16*)take((size_t)NB * NN * NC * 2);
  __hip_bfloat16* Bh = (__hip_bfloat16*)take((size_t)NB * NN * NC * 2);
  __hip_bfloat16* Bl = (__hip_bfloat16*)take((size_t)NB * NN * NC * 2);
  float* uu   = (float*)take((size_t)NB * VST * 4);
  float* v0   = (float*)take((size_t)NB * VST * 4);
  float* v1   = (float*)take((size_t)NB * VST * 4);
  float* part = (float*)take((size_t)NB * 512 * NN * 4);
  float* tkv  = (float*)take((size_t)NB * NN * NK * 4);
  int*   tki  = (int*)take((size_t)NB * NN * NK * 4);
  float* geo  = (float*)take((size_t)NB * NN * NK * 4);
  (void)off; (void)ws_size;

  norm_split<<<dim3(2 * NB * NN), 64, 0, stream>>>(fA, fB, Ah, Al, Bh, Bl, v0);
  gemm_mfma<<<dim3(NN / 128, NN / 128, NB), 256, 0, stream>>>(Ah, Al, Bh, Bl, sim);
  for (int it = 0; it < 5; it++) {
    float* vin  = (it & 1) ? v1 : v0;
    float* vout = (it & 1) ? v0 : v1;
    // serpentine: even iters reversed (gemm wrote tail last; pass4 rev ends at b0row0
    // so finalize's forward sweep starts on resident lines)
    int rev = ((it & 1) == 0) ? 1 : 0;
    sink_fused<<<dim3(512, NB), 512, 0, stream>>>(sim, vin, uu, part, rev);
    sink_stage2<<<dim3(128, NB), 256, 0, stream>>>(part, vin, uu, vout);
  }
  finalize_rows<<<dim3(NN, NB), 256, 0, stream>>>(sim, uu, v1, tkv, tki, ent);
  geo_kernel<<<dim3(NK, 8, NB), 256, 0, stream>>>(tki, pA, pB, geo);
  combine_kernel<<<dim3((NB * NN) / 256), 256, 0, stream>>>(tkv, geo, tki, pB, warp);
}

// Round 8
// 386.260 us; speedup vs baseline: 1.0226x; 1.0226x over previous
//
#include <hip/hip_runtime.h>
#include <hip/hip_bf16.h>

// AgriMatcher: normalize(+bf16 hi/lo split, fused v0-init) -> MFMA cosine-sim GEMM ->
// fused fp32 log-Sinkhorn(5) (u+v in one matrix pass per iteration) ->
// per-row top-8 (u64-key selection, exact ordering) + entropy ->
// banded 7x7 local variance geometric score -> softmax warp.
// B=2, N=4096=64x64, C=128, K=8, TEMP=0.05, RADIUS=3.
//
// R2: cg-coop Sinkhorn spilled (VGPR capped 64 by launch_bounds(512,4) -> scratch) -> 910us.
// R4: divergent hierarchical top-8 LOST (81->88us): winner-lane rescan broke ILP.
// R5: branchless sorted-groups finalize WON (~-15us); nt hints on part LOST (+14). Reverted nt.
// R7: serpentine pass direction NEUTRAL (+2.5us noise): 1024 blocks are fully co-resident,
//     so there is no temporal sweep direction to exploit. Reverted.
// R8: sink_fused had the SAME (512,4) bound as R2's spiller -> VGPR cap 64 < E[8][8] live
//     across barriers. Relax to (512,2): VGPR cap 128, no spill; 4 waves/SIMD still
//     plenty for a memory-bound streaming kernel. Bit-identical arithmetic.

#define NB 2
#define NN 4096
#define NC 128
#define NK 8
#define VST 4104   // padded stride for u/v vectors

constexpr float INV_TEMP   = 20.0f;
constexpr float NORM_CONST = -9.010913347279289f;    // -log(8192)
constexpr float LOG_DUST   = -0.6931471805599453f;   // log(4096)-log(8192)

typedef __attribute__((ext_vector_type(8))) short bf16x8;
typedef __attribute__((ext_vector_type(4))) float f32x4;

// ---------------- 1. L2 normalize rows + bf16 hi/lo split (+ v0 zero-fill) ----------------
__global__ void norm_split(const float* __restrict__ fa, const float* __restrict__ fb,
                           __hip_bfloat16* __restrict__ Ah, __hip_bfloat16* __restrict__ Al,
                           __hip_bfloat16* __restrict__ Bh, __hip_bfloat16* __restrict__ Bl,
                           float* __restrict__ v0) {
  int row = blockIdx.x;
  int t = threadIdx.x;
  // fused init: first 129 blocks zero v0 (read only 2 kernels later)
  if (row < (NB * VST + 63) / 64) {
    int i = row * 64 + t;
    if (i < NB * VST) v0[i] = 0.0f;
  }
  bool isB = row >= NB * NN;
  int base = isB ? row - NB * NN : row;
  const float* src = (isB ? fb : fa) + (size_t)base * NC;
  __hip_bfloat16* dh = (isB ? Bh : Ah) + (size_t)base * NC;
  __hip_bfloat16* dl = (isB ? Bl : Al) + (size_t)base * NC;
  float x0 = src[t], x1 = src[t + 64];
  float ss = x0 * x0 + x1 * x1;
  #pragma unroll
  for (int o = 32; o; o >>= 1) ss += __shfl_xor(ss, o);
  float nrm = fmaxf(sqrtf(ss), 1e-12f);
  float y0 = x0 / nrm, y1 = x1 / nrm;
  __hip_bfloat16 h0 = __float2bfloat16(y0);
  __hip_bfloat16 h1 = __float2bfloat16(y1);
  dh[t] = h0;      dl[t] = __float2bfloat16(y0 - __bfloat162float(h0));
  dh[t + 64] = h1; dl[t + 64] = __float2bfloat16(y1 - __bfloat162float(h1));
}

// ---------------- 2. MFMA GEMM: sim = A.B^T via bf16 hi/lo split ----------------
__launch_bounds__(256, 2)
__global__ void gemm_mfma(const __hip_bfloat16* __restrict__ Ah, const __hip_bfloat16* __restrict__ Al,
                          const __hip_bfloat16* __restrict__ Bh, const __hip_bfloat16* __restrict__ Bl,
                          float* __restrict__ sim) {
  __shared__ __hip_bfloat16 sAh[128 * 64], sAl[128 * 64];
  __shared__ __hip_bfloat16 sBh[128 * 64], sBl[128 * 64];
  const int b = blockIdx.z, m0 = blockIdx.y * 128, n0 = blockIdx.x * 128;
  const int t = threadIdx.x;
  const int wid = t >> 6, l = t & 63, q = l >> 4, lm = l & 15;
  const int wm = (wid >> 1) * 64, wn = (wid & 1) * 64;
  f32x4 acc[4][4] = {};
  const __hip_bfloat16* gAh = Ah + ((size_t)b * NN + m0) * NC;
  const __hip_bfloat16* gAl = Al + ((size_t)b * NN + m0) * NC;
  const __hip_bfloat16* gBh = Bh + ((size_t)b * NN + n0) * NC;
  const __hip_bfloat16* gBl = Bl + ((size_t)b * NN + n0) * NC;

  for (int koff = 0; koff < NC; koff += 64) {
    #pragma unroll
    for (int ii = 0; ii < 4; ii++) {
      int id = t + 256 * ii;
      int row = id >> 3, cc = id & 7;
      int gofs = row * NC + koff + cc * 8;
      int lofs = row * 64 + ((cc ^ (row & 7)) << 3);
      *(float4*)&sAh[lofs] = *(const float4*)(gAh + gofs);
      *(float4*)&sAl[lofs] = *(const float4*)(gAl + gofs);
      *(float4*)&sBh[lofs] = *(const float4*)(gBh + gofs);
      *(float4*)&sBl[lofs] = *(const float4*)(gBl + gofs);
    }
    __syncthreads();
    #pragma unroll
    for (int ks = 0; ks < 2; ks++) {
      int cc = ks * 4 + q;
      bf16x8 a_h[4], a_l[4], b_h[4], b_l[4];
      #pragma unroll
      for (int i = 0; i < 4; i++) {
        int r = wm + i * 16 + lm;
        int ro = r * 64 + ((cc ^ (r & 7)) << 3);
        a_h[i] = *(const bf16x8*)&sAh[ro];
        a_l[i] = *(const bf16x8*)&sAl[ro];
        int n = wn + i * 16 + lm;
        int no = n * 64 + ((cc ^ (n & 7)) << 3);
        b_h[i] = *(const bf16x8*)&sBh[no];
        b_l[i] = *(const bf16x8*)&sBl[no];
      }
      #pragma unroll
      for (int i = 0; i < 4; i++) {
        #pragma unroll
        for (int j = 0; j < 4; j++) {
          acc[i][j] = __builtin_amdgcn_mfma_f32_16x16x32_bf16(a_h[i], b_h[j], acc[i][j], 0, 0, 0);
          acc[i][j] = __builtin_amdgcn_mfma_f32_16x16x32_bf16(a_h[i], b_l[j], acc[i][j], 0, 0, 0);
          acc[i][j] = __builtin_amdgcn_mfma_f32_16x16x32_bf16(a_l[i], b_h[j], acc[i][j], 0, 0, 0);
        }
      }
    }
    __syncthreads();
  }
  // C/D layout (m89-verified): col = lane&15, row = (lane>>4)*4 + reg
  float* ob = sim + (size_t)b * NN * NN;
  #pragma unroll
  for (int i = 0; i < 4; i++) {
    #pragma unroll
    for (int j = 0; j < 4; j++) {
      int col = n0 + wn + j * 16 + lm;
      #pragma unroll
      for (int reg = 0; reg < 4; reg++) {
        int r = m0 + wm + i * 16 + q * 4 + reg;
        ob[(size_t)r * NN + col] = acc[i][j][reg];
      }
    }
  }
}

// ---------------- 3a. fused Sinkhorn pass: u for 8 rows + column partials ----------------
// (512,2): VGPR cap 128 so E[8][8] stays in registers across both barriers (no scratch).
__launch_bounds__(512, 2)
__global__ void sink_fused(const float* __restrict__ sim, const float* __restrict__ vin,
                           float* __restrict__ u, float* __restrict__ part) {
  int blk = blockIdx.x, b = blockIdx.y, t = threadIdx.x;
  int r0 = blk * 8, c0 = t * 8;
  const float* vb = vin + b * VST;
  const float* srow0 = sim + ((size_t)b * NN + r0) * NN + c0;

  float4 va0 = *(const float4*)(vb + c0);
  float4 va1 = *(const float4*)(vb + c0 + 4);
  float vm[8] = {va0.x - 30.0f, va0.y - 30.0f, va0.z - 30.0f, va0.w - 30.0f,
                 va1.x - 30.0f, va1.y - 30.0f, va1.z - 30.0f, va1.w - 30.0f};
  float E[8][8];
  float rp[8];
  #pragma unroll
  for (int r = 0; r < 8; r++) {
    const float4* sp = (const float4*)(srow0 + (size_t)r * NN);
    float4 s0 = sp[0], s1 = sp[1];
    E[r][0] = __expf(fmaf(s0.x, INV_TEMP, vm[0]));
    E[r][1] = __expf(fmaf(s0.y, INV_TEMP, vm[1]));
    E[r][2] = __expf(fmaf(s0.z, INV_TEMP, vm[2]));
    E[r][3] = __expf(fmaf(s0.w, INV_TEMP, vm[3]));
    E[r][4] = __expf(fmaf(s1.x, INV_TEMP, vm[4]));
    E[r][5] = __expf(fmaf(s1.y, INV_TEMP, vm[5]));
    E[r][6] = __expf(fmaf(s1.z, INV_TEMP, vm[6]));
    E[r][7] = __expf(fmaf(s1.w, INV_TEMP, vm[7]));
    rp[r] = ((E[r][0] + E[r][1]) + (E[r][2] + E[r][3]))
          + ((E[r][4] + E[r][5]) + (E[r][6] + E[r][7]));
  }
  #pragma unroll
  for (int r = 0; r < 8; r++) {
    #pragma unroll
    for (int o = 1; o < 64; o <<= 1) rp[r] += __shfl_xor(rp[r], o);
  }
  __shared__ float ws[8][8];   // [wave][row]
  __shared__ float eus[8];
  int w = t >> 6;
  if ((t & 63) == 0) {
    #pragma unroll
    for (int r = 0; r < 8; r++) ws[w][r] = rp[r];
  }
  __syncthreads();
  if (t < 8) {
    float S = 0.0f;
    #pragma unroll
    for (int ww = 0; ww < 8; ww++) S += ws[ww][t];
    S += __expf(vb[NN] - 30.0f);               // dustbin column term
    float ur = NORM_CONST - 30.0f - __logf(S);
    u[b * VST + r0 + t] = ur;
    eus[t] = __expf(ur);
  }
  __syncthreads();
  float eu[8];
  #pragma unroll
  for (int r = 0; r < 8; r++) eu[r] = eus[r];
  float outp[8];
  #pragma unroll
  for (int c = 0; c < 8; c++) {
    float acc = E[0][c] * eu[0];
    #pragma unroll
    for (int r = 1; r < 8; r++) acc = fmaf(E[r][c], eu[r], acc);
    outp[c] = acc * __expf(-30.0f - vm[c]);    // * exp(-v_c)
  }
  float* pp = part + ((size_t)b * 512 + blk) * NN + c0;
  *(float4*)pp       = make_float4(outp[0], outp[1], outp[2], outp[3]);
  *(float4*)(pp + 4) = make_float4(outp[4], outp[5], outp[6], outp[7]);
}

// ---------------- 3b. stage2: reduce column partials -> v; dustbins ----------------
__launch_bounds__(256)
__global__ void sink_stage2(const float* __restrict__ part, const float* __restrict__ vin,
                            const float* __restrict__ u, float* __restrict__ vout) {
  int b = blockIdx.y, t = threadIdx.x;
  const float* vb = vin + b * VST;
  // u_dust = LOG_DUST - 30 - log( sum_c exp(v_c-30) + exp(v_dust-30) )
  float sv = 0.0f;
  #pragma unroll
  for (int i = 0; i < 16; i++) sv += __expf(vb[t + (i << 8)] - 30.0f);
  #pragma unroll
  for (int o = 1; o < 64; o <<= 1) sv += __shfl_xor(sv, o);
  __shared__ float sa[4];
  if ((t & 63) == 0) sa[t >> 6] = sv;
  __syncthreads();
  float S_v = sa[0] + sa[1] + sa[2] + sa[3] + __expf(vb[NN] - 30.0f);
  float eud = __expf(LOG_DUST - 60.0f - __logf(S_v));  // exp(u_dust - 30)

  int c = t & 31, h = t >> 5;
  int col = blockIdx.x * 32 + c;
  const float* pb = part + (size_t)b * 512 * NN + col;
  float acc = 0.0f;
  #pragma unroll 4
  for (int j = 0; j < 64; j++) acc += pb[(size_t)(h * 64 + j) * NN];
  __shared__ float red[256];
  red[t] = acc;
  __syncthreads();
  if (h == 0) {
    #pragma unroll
    for (int g = 1; g < 8; g++) acc += red[g * 32 + c];
    vout[b * VST + col] = NORM_CONST - 30.0f - __logf(acc + eud);
  }
  if (blockIdx.x == 0) {
    const float* ub = u + b * VST;
    float su = 0.0f;
    #pragma unroll
    for (int i = 0; i < 16; i++) su += __expf(ub[t + (i << 8)] - 30.0f);
    #pragma unroll
    for (int o = 1; o < 64; o <<= 1) su += __shfl_xor(su, o);
    __shared__ float sb[4];
    if ((t & 63) == 0) sb[t >> 6] = su;
    __syncthreads();
    if (t == 0)
      vout[b * VST + NN] = LOG_DUST - 30.0f - __logf(sb[0] + sb[1] + sb[2] + sb[3] + eud);
  }
}

// ---------------- 4. finalize: top-8 via u64 keys (exact ordering), entropy ----------------
// R5: branchless sorted-groups selection. Each lane pre-sorts its 4 groups of 4 keys
// (5-CE network, pure ILP). Per round: global max = max of 4 group heads (3 u64-max),
// butterfly, then a uniform shift-register pop in the winner's group. Keys are unique
// (index in low bits) -> emitted sequence identical to the flat 16-key scan.
__launch_bounds__(256)
__global__ void finalize_rows(const float* __restrict__ sim, const float* __restrict__ u,
                              const float* __restrict__ v, float* __restrict__ tkv,
                              int* __restrict__ tki, float* __restrict__ ent) {
  int m = blockIdx.x, b = blockIdx.y, t = threadIdx.x;
  const float4* srow = (const float4*)(sim + ((size_t)b * NN + m) * NN);
  const float4* v4 = (const float4*)(v + b * VST);
  float um = u[b * VST + m];
  unsigned long long key[16];
  float T1 = 0.0f, T2 = 0.0f;
  #pragma unroll
  for (int i = 0; i < 4; i++) {
    int idx = t + (i << 8);
    float4 s = srow[idx], vv = v4[idx];
    unsigned n0 = 4u * (unsigned)idx;
    float z, e;
    unsigned zb, k;
    z = fmaf(s.x, INV_TEMP, vv.x + um); e = __expf(z); T1 += e; T2 = fmaf(e, z, T2);
    zb = __float_as_uint(z); k = (zb & 0x80000000u) ? ~zb : (zb | 0x80000000u);
    key[4 * i + 0] = ((unsigned long long)k << 32) | (unsigned)(~n0);
    z = fmaf(s.y, INV_TEMP, vv.y + um); e = __expf(z); T1 += e; T2 = fmaf(e, z, T2);
    zb = __float_as_uint(z); k = (zb & 0x80000000u) ? ~zb : (zb | 0x80000000u);
    key[4 * i + 1] = ((unsigned long long)k << 32) | (unsigned)(~(n0 + 1));
    z = fmaf(s.z, INV_TEMP, vv.z + um); e = __expf(z); T1 += e; T2 = fmaf(e, z, T2);
    zb = __float_as_uint(z); k = (zb & 0x80000000u) ? ~zb : (zb | 0x80000000u);
    key[4 * i + 2] = ((unsigned long long)k << 32) | (unsigned)(~(n0 + 2));
    z = fmaf(s.w, INV_TEMP, vv.w + um); e = __expf(z); T1 += e; T2 = fmaf(e, z, T2);
    zb = __float_as_uint(z); k = (zb & 0x80000000u) ? ~zb : (zb | 0x80000000u);
    key[4 * i + 3] = ((unsigned long long)k << 32) | (unsigned)(~(n0 + 3));
  }
  #pragma unroll
  for (int o = 1; o < 64; o <<= 1) { T1 += __shfl_xor(T1, o); T2 += __shfl_xor(T2, o); }

  // pre-sort each group of 4 descending (sorting network [(0,1)(2,3)(0,2)(1,3)(1,2)])
  #pragma unroll
  for (int gi = 0; gi < 4; gi++) {
    unsigned long long k0 = key[4 * gi], k1 = key[4 * gi + 1];
    unsigned long long k2 = key[4 * gi + 2], k3 = key[4 * gi + 3];
    unsigned long long hi, lo;
    hi = k0 > k1 ? k0 : k1; lo = k0 > k1 ? k1 : k0; k0 = hi; k1 = lo;
    hi = k2 > k3 ? k2 : k3; lo = k2 > k3 ? k3 : k2; k2 = hi; k3 = lo;
    hi = k0 > k2 ? k0 : k2; lo = k0 > k2 ? k2 : k0; k0 = hi; k2 = lo;
    hi = k1 > k3 ? k1 : k3; lo = k1 > k3 ? k3 : k1; k1 = hi; k3 = lo;
    hi = k1 > k2 ? k1 : k2; lo = k1 > k2 ? k2 : k1; k1 = hi; k2 = lo;
    key[4 * gi] = k0; key[4 * gi + 1] = k1; key[4 * gi + 2] = k2; key[4 * gi + 3] = k3;
  }

  unsigned long long wv[8];
  #pragma unroll
  for (int r = 0; r < 8; r++) {
    unsigned long long m01 = key[0] > key[4] ? key[0] : key[4];
    unsigned long long m23 = key[8] > key[12] ? key[8] : key[12];
    unsigned long long mx = m01 > m23 ? m01 : m23;
    #pragma unroll
    for (int o = 1; o < 64; o <<= 1) {
      unsigned long long om = __shfl_xor(mx, o);
      mx = (om > mx) ? om : mx;
    }
    wv[r] = mx;
    // branchless pop: only the winner's group head can equal mx (keys unique)
    #pragma unroll
    for (int gi = 0; gi < 4; gi++) {
      bool c = (key[4 * gi] == mx);
      key[4 * gi]     = c ? key[4 * gi + 1] : key[4 * gi];
      key[4 * gi + 1] = c ? key[4 * gi + 2] : key[4 * gi + 1];
      key[4 * gi + 2] = c ? key[4 * gi + 3] : key[4 * gi + 2];
      key[4 * gi + 3] = c ? 0ull            : key[4 * gi + 3];
    }
  }

  __shared__ unsigned long long lv[4][8];
  __shared__ unsigned long long fv[8];
  __shared__ float sT1[4], sT2[4];
  int wid = t >> 6;
  if ((t & 63) == 0) {
    sT1[wid] = T1; sT2[wid] = T2;
    #pragma unroll
    for (int j = 0; j < 8; j++) lv[wid][j] = wv[j];
  }
  __syncthreads();
  if (t == 0) {
    int p[4] = {0, 0, 0, 0};
    for (int k2 = 0; k2 < 8; k2++) {
      unsigned long long best = 0ull; int bw = 0;
      #pragma unroll
      for (int w = 0; w < 4; w++) {
        if (p[w] < 8 && lv[w][p[w]] > best) { best = lv[w][p[w]]; bw = w; }
      }
      fv[k2] = best; p[bw]++;
    }
  }
  __syncthreads();
  size_t ro = ((size_t)b * NN + m) * NK;
  if (t < 8) {
    unsigned long long kk = fv[t];
    unsigned kh = (unsigned)(kk >> 32);
    unsigned zb = (kh & 0x80000000u) ? (kh & 0x7FFFFFFFu) : ~kh;
    tkv[ro + t] = __expf(__uint_as_float(zb));
    tki[ro + t] = (int)(~(unsigned)kk);
  }
  if (t == 0) {
    float T1t = sT1[0] + sT1[1] + sT1[2] + sT1[3];
    float T2t = sT2[0] + sT2[1] + sT2[2] + sT2[3];
    float denom = T1t + 1e-8f;
    float ld = __logf(denom);
    ent[b * NN + m] = (T1t * ld - T2t) / denom;
  }
}

// ---------------- 5. geometric score: banded 7x7 local variance ----------------
__launch_bounds__(256)
__global__ void geo_kernel(const int* __restrict__ tki, const float* __restrict__ posA,
                           const float* __restrict__ posB, float* __restrict__ geo) {
  int k = blockIdx.x, band = blockIdx.y, b = blockIdx.z, t = threadIdx.x;
  int r0 = band * 8, rlo = r0 - 3;
  __shared__ float s1[14 * 64], s2[14 * 64], h1[14 * 64], h2[14 * 64];
  const float* pA = posA + (size_t)b * NN * 2;
  const float* pB = posB + (size_t)b * NN * 2;
  const int* idx = tki + (size_t)b * NN * NK + k;
  for (int e = t; e < 14 * 64; e += 256) {
    int rr = rlo + (e >> 6), w = e & 63;
    float v1 = 0.0f, v2 = 0.0f;
    if (rr >= 0 && rr < 64) {
      int n = rr * 64 + w;
      int j = idx[(size_t)n * NK];
      float dx = pB[(size_t)j * 2]     - pA[(size_t)n * 2];
      float dy = pB[(size_t)j * 2 + 1] - pA[(size_t)n * 2 + 1];
      v1 = dx + dy;
      v2 = dx * dx + dy * dy;
    }
    s1[e] = v1; s2[e] = v2;
  }
  __syncthreads();
  for (int e = t; e < 14 * 64; e += 256) {
    int w = e & 63, base = e - w;
    float a1 = 0.0f, a2 = 0.0f;
    for (int dw = -3; dw <= 3; dw++) {
      int ww = w + dw;
      if (ww >= 0 && ww < 64) { a1 += s1[base + ww]; a2 += s2[base + ww]; }
    }
    h1[e] = a1; h2[e] = a2;
  }
  __syncthreads();
  for (int o = t; o < 8 * 64; o += 256) {
    int lr = (o >> 6) + 3, w = o & 63;
    int e = lr * 64 + w;
    float b1 = 0.0f, b2 = 0.0f;
    #pragma unroll
    for (int dh = -3; dh <= 3; dh++) { b1 += h1[e + dh * 64]; b2 += h2[e + dh * 64]; }
    float mean = b1 * (1.0f / 98.0f);
    float var = (b2 - b1 * mean) * (1.0f / 97.0f);
    int n = (r0 + (o >> 6)) * 64 + w;
    geo[((size_t)b * NN + n) * NK + k] = 1.0f / (1.0f + var * 100.0f);
  }
}

// ---------------- 6. combine: softmax over K, weighted warp ----------------
__launch_bounds__(256)
__global__ void combine_kernel(const float* __restrict__ tkv, const float* __restrict__ geo,
                               const int* __restrict__ tki, const float* __restrict__ posB,
                               float* __restrict__ warp) {
  int id = blockIdx.x * 256 + threadIdx.x;
  int b = id / NN;
  const float* vals = tkv + (size_t)id * NK;
  const float* g    = geo + (size_t)id * NK;
  const int*   ix   = tki + (size_t)id * NK;
  const float* pB   = posB + (size_t)b * NN * 2;
  float l[8], mx = -3.0e38f;
  #pragma unroll
  for (int j = 0; j < 8; j++) {
    l[j] = (vals[j] + 1.5f * g[j]) * INV_TEMP;
    mx = fmaxf(mx, l[j]);
  }
  float sw = 0.0f, wx = 0.0f, wy = 0.0f;
  #pragma unroll
  for (int j = 0; j < 8; j++) {
    float w = __expf(l[j] - mx);
    int jj = ix[j];
    sw += w;
    wx = fmaf(w, pB[(size_t)jj * 2], wx);
    wy = fmaf(w, pB[(size_t)jj * 2 + 1], wy);
  }
  warp[(size_t)id * 2]     = wx / sw;
  warp[(size_t)id * 2 + 1] = wy / sw;
}

extern "C" void kernel_launch(void* const* d_in, const int* in_sizes, int n_in,
                              void* d_out, int out_size, void* d_ws, size_t ws_size,
                              hipStream_t stream) {
  const float* fA = (const float*)d_in[0];
  const float* fB = (const float*)d_in[1];
  const float* pA = (const float*)d_in[2];
  const float* pB = (const float*)d_in[3];

  float* out  = (float*)d_out;
  float* warp = out;                       // [B,N,2]
  float* ent  = out + (size_t)NB * NN * 2; // [B,N]
  float* sim  = ent + (size_t)NB * NN;     // [B,N,N] raw_sim (also Sinkhorn cost)

  size_t off = 0;
  auto take = [&](size_t bytes) {
    void* p = (char*)d_ws + off;
    off = (off + bytes + 255) & ~(size_t)255;
    return p;
  };
  __hip_bfloat16* Ah = (__hip_bfloat16*)take((size_t)NB * NN * NC * 2);
  __hip_bfloat16* Al = (__hip_bfloat16*)take((size_t)NB * NN * NC * 2);
  __hip_bfloat16* Bh = (__hip_bfloat16*)take((size_t)NB * NN * NC * 2);
  __hip_bfloat16* Bl = (__hip_bfloat16*)take((size_t)NB * NN * NC * 2);
  float* uu   = (float*)take((size_t)NB * VST * 4);
  float* v0   = (float*)take((size_t)NB * VST * 4);
  float* v1   = (float*)take((size_t)NB * VST * 4);
  float* part = (float*)take((size_t)NB * 512 * NN * 4);
  float* tkv  = (float*)take((size_t)NB * NN * NK * 4);
  int*   tki  = (int*)take((size_t)NB * NN * NK * 4);
  float* geo  = (float*)take((size_t)NB * NN * NK * 4);
  (void)off; (void)ws_size;

  norm_split<<<dim3(2 * NB * NN), 64, 0, stream>>>(fA, fB, Ah, Al, Bh, Bl, v0);
  gemm_mfma<<<dim3(NN / 128, NN / 128, NB), 256, 0, stream>>>(Ah, Al, Bh, Bl, sim);
  for (int it = 0; it < 5; it++) {
    float* vin  = (it & 1) ? v1 : v0;
    float* vout = (it & 1) ? v0 : v1;
    sink_fused<<<dim3(NN / 8, NB), 512, 0, stream>>>(sim, vin, uu, part);
    sink_stage2<<<dim3(128, NB), 256, 0, stream>>>(part, vin, uu, vout);
  }
  finalize_rows<<<dim3(NN, NB), 256, 0, stream>>>(sim, uu, v1, tkv, tki, ent);
  geo_kernel<<<dim3(NK, 8, NB), 256, 0, stream>>>(tki, pA, pB, geo);
  combine_kernel<<<dim3((NB * NN) / 256), 256, 0, stream>>>(tkv, geo, tki, pB, warp);
}

// Round 9
// 371.528 us; speedup vs baseline: 1.0631x; 1.0397x over previous
//
#include <hip/hip_runtime.h>
#include <hip/hip_bf16.h>

// AgriMatcher: normalize(+bf16 hi/lo split, fused v0-init) -> MFMA cosine-sim GEMM
// (writes fp32 sim output + u16 log-domain quantized copy) -> fused fp32 log-Sinkhorn(5)
// reading the u16 copy (half traffic, z-error <= 3.1e-4) -> per-row top-8 on fp32 sim
// (u64 keys, exact ordering) + entropy -> banded 7x7 local variance -> softmax warp.
// B=2, N=4096=64x64, C=128, K=8, TEMP=0.05, RADIUS=3.
//
// R2: cg-coop Sinkhorn spilled (VGPR cap 64) -> 910us. Reverted.
// R4: divergent hierarchical top-8 LOST: broke ILP. R5: branchless sorted-groups WON (~-15us);
//     nt hints on part LOST (+14, part is next kernel's working set). R7: serpentine NEUTRAL
//     (grid fully co-resident -> no sweep direction). R8: sink (512,4)->(512,2) WON (-6us, spill).
// R9: u16 Sinkhorn matrix. Sink only consumes sim via exp(20s+v-30); quantize 20s to u16
//     (resolution 6.3e-4) in gemm epilogue. 5 passes read 67MB instead of 134MB (-268MB net).
//     finalize still uses fp32 sim for selection; u/v perturbed ~3e-4 (<< rank-8 gaps).

#define NB 2
#define NN 4096
#define NC 128
#define NK 8
#define VST 4104   // padded stride for u/v vectors

constexpr float INV_TEMP   = 20.0f;
constexpr float NORM_CONST = -9.010913347279289f;    // -log(8192)
constexpr float LOG_DUST   = -0.6931471805599453f;   // log(4096)-log(8192)
constexpr float QSCALE     = 65535.0f / 41.0f;       // (20s+20.5) in [0.49,40.51] -> u16
constexpr float QINV       = 41.0f / 65535.0f;

typedef __attribute__((ext_vector_type(8))) short bf16x8;
typedef __attribute__((ext_vector_type(8))) unsigned short u16x8;
typedef __attribute__((ext_vector_type(4))) float f32x4;

// ---------------- 1. L2 normalize rows + bf16 hi/lo split (+ v0 zero-fill) ----------------
__global__ void norm_split(const float* __restrict__ fa, const float* __restrict__ fb,
                           __hip_bfloat16* __restrict__ Ah, __hip_bfloat16* __restrict__ Al,
                           __hip_bfloat16* __restrict__ Bh, __hip_bfloat16* __restrict__ Bl,
                           float* __restrict__ v0) {
  int row = blockIdx.x;
  int t = threadIdx.x;
  // fused init: first 129 blocks zero v0 (read only 2 kernels later)
  if (row < (NB * VST + 63) / 64) {
    int i = row * 64 + t;
    if (i < NB * VST) v0[i] = 0.0f;
  }
  bool isB = row >= NB * NN;
  int base = isB ? row - NB * NN : row;
  const float* src = (isB ? fb : fa) + (size_t)base * NC;
  __hip_bfloat16* dh = (isB ? Bh : Ah) + (size_t)base * NC;
  __hip_bfloat16* dl = (isB ? Bl : Al) + (size_t)base * NC;
  float x0 = src[t], x1 = src[t + 64];
  float ss = x0 * x0 + x1 * x1;
  #pragma unroll
  for (int o = 32; o; o >>= 1) ss += __shfl_xor(ss, o);
  float nrm = fmaxf(sqrtf(ss), 1e-12f);
  float y0 = x0 / nrm, y1 = x1 / nrm;
  __hip_bfloat16 h0 = __float2bfloat16(y0);
  __hip_bfloat16 h1 = __float2bfloat16(y1);
  dh[t] = h0;      dl[t] = __float2bfloat16(y0 - __bfloat162float(h0));
  dh[t + 64] = h1; dl[t + 64] = __float2bfloat16(y1 - __bfloat162float(h1));
}

// ---------------- 2. MFMA GEMM: sim = A.B^T (fp32 out) + u16 quantized copy ----------------
__launch_bounds__(256, 2)
__global__ void gemm_mfma(const __hip_bfloat16* __restrict__ Ah, const __hip_bfloat16* __restrict__ Al,
                          const __hip_bfloat16* __restrict__ Bh, const __hip_bfloat16* __restrict__ Bl,
                          float* __restrict__ sim, unsigned short* __restrict__ s16) {
  __shared__ __hip_bfloat16 sAh[128 * 64], sAl[128 * 64];
  __shared__ __hip_bfloat16 sBh[128 * 64], sBl[128 * 64];
  const int b = blockIdx.z, m0 = blockIdx.y * 128, n0 = blockIdx.x * 128;
  const int t = threadIdx.x;
  const int wid = t >> 6, l = t & 63, q = l >> 4, lm = l & 15;
  const int wm = (wid >> 1) * 64, wn = (wid & 1) * 64;
  f32x4 acc[4][4] = {};
  const __hip_bfloat16* gAh = Ah + ((size_t)b * NN + m0) * NC;
  const __hip_bfloat16* gAl = Al + ((size_t)b * NN + m0) * NC;
  const __hip_bfloat16* gBh = Bh + ((size_t)b * NN + n0) * NC;
  const __hip_bfloat16* gBl = Bl + ((size_t)b * NN + n0) * NC;

  for (int koff = 0; koff < NC; koff += 64) {
    #pragma unroll
    for (int ii = 0; ii < 4; ii++) {
      int id = t + 256 * ii;
      int row = id >> 3, cc = id & 7;
      int gofs = row * NC + koff + cc * 8;
      int lofs = row * 64 + ((cc ^ (row & 7)) << 3);
      *(float4*)&sAh[lofs] = *(const float4*)(gAh + gofs);
      *(float4*)&sAl[lofs] = *(const float4*)(gAl + gofs);
      *(float4*)&sBh[lofs] = *(const float4*)(gBh + gofs);
      *(float4*)&sBl[lofs] = *(const float4*)(gBl + gofs);
    }
    __syncthreads();
    #pragma unroll
    for (int ks = 0; ks < 2; ks++) {
      int cc = ks * 4 + q;
      bf16x8 a_h[4], a_l[4], b_h[4], b_l[4];
      #pragma unroll
      for (int i = 0; i < 4; i++) {
        int r = wm + i * 16 + lm;
        int ro = r * 64 + ((cc ^ (r & 7)) << 3);
        a_h[i] = *(const bf16x8*)&sAh[ro];
        a_l[i] = *(const bf16x8*)&sAl[ro];
        int n = wn + i * 16 + lm;
        int no = n * 64 + ((cc ^ (n & 7)) << 3);
        b_h[i] = *(const bf16x8*)&sBh[no];
        b_l[i] = *(const bf16x8*)&sBl[no];
      }
      #pragma unroll
      for (int i = 0; i < 4; i++) {
        #pragma unroll
        for (int j = 0; j < 4; j++) {
          acc[i][j] = __builtin_amdgcn_mfma_f32_16x16x32_bf16(a_h[i], b_h[j], acc[i][j], 0, 0, 0);
          acc[i][j] = __builtin_amdgcn_mfma_f32_16x16x32_bf16(a_h[i], b_l[j], acc[i][j], 0, 0, 0);
          acc[i][j] = __builtin_amdgcn_mfma_f32_16x16x32_bf16(a_l[i], b_h[j], acc[i][j], 0, 0, 0);
        }
      }
    }
    __syncthreads();
  }
  // C/D layout (m89-verified): col = lane&15, row = (lane>>4)*4 + reg
  float* ob = sim + (size_t)b * NN * NN;
  unsigned short* qb = s16 + (size_t)b * NN * NN;
  #pragma unroll
  for (int i = 0; i < 4; i++) {
    #pragma unroll
    for (int j = 0; j < 4; j++) {
      int col = n0 + wn + j * 16 + lm;
      #pragma unroll
      for (int reg = 0; reg < 4; reg++) {
        int r = m0 + wm + i * 16 + q * 4 + reg;
        float s = acc[i][j][reg];
        ob[(size_t)r * NN + col] = s;
        // q = round((20s + 20.5)*QSCALE); s in [-1.004,1.004] -> q in (780,64900), no clamp needed
        qb[(size_t)r * NN + col] =
            (unsigned short)__float2uint_rn(fmaf(s, INV_TEMP, 20.5f) * QSCALE);
      }
    }
  }
}

// ---------------- 3a. fused Sinkhorn pass: u for 8 rows + column partials ----------------
// Reads the u16 quantized matrix: E = exp(q*QINV + (v - 50.5)) == exp(20s' + v - 30),
// |20s' - 20s| <= 3.1e-4. (512,2): VGPR cap 128 so E[8][8] stays in regs (no scratch).
__launch_bounds__(512, 2)
__global__ void sink_fused(const unsigned short* __restrict__ s16, const float* __restrict__ vin,
                           float* __restrict__ u, float* __restrict__ part) {
  int blk = blockIdx.x, b = blockIdx.y, t = threadIdx.x;
  int r0 = blk * 8, c0 = t * 8;
  const float* vb = vin + b * VST;
  const unsigned short* srow0 = s16 + ((size_t)b * NN + r0) * NN + c0;

  float4 va0 = *(const float4*)(vb + c0);
  float4 va1 = *(const float4*)(vb + c0 + 4);
  float vmk[8] = {va0.x - 50.5f, va0.y - 50.5f, va0.z - 50.5f, va0.w - 50.5f,
                  va1.x - 50.5f, va1.y - 50.5f, va1.z - 50.5f, va1.w - 50.5f};
  float E[8][8];
  float rp[8];
  #pragma unroll
  for (int r = 0; r < 8; r++) {
    u16x8 qv = *(const u16x8*)(srow0 + (size_t)r * NN);
    E[r][0] = __expf(fmaf((float)qv[0], QINV, vmk[0]));
    E[r][1] = __expf(fmaf((float)qv[1], QINV, vmk[1]));
    E[r][2] = __expf(fmaf((float)qv[2], QINV, vmk[2]));
    E[r][3] = __expf(fmaf((float)qv[3], QINV, vmk[3]));
    E[r][4] = __expf(fmaf((float)qv[4], QINV, vmk[4]));
    E[r][5] = __expf(fmaf((float)qv[5], QINV, vmk[5]));
    E[r][6] = __expf(fmaf((float)qv[6], QINV, vmk[6]));
    E[r][7] = __expf(fmaf((float)qv[7], QINV, vmk[7]));
    rp[r] = ((E[r][0] + E[r][1]) + (E[r][2] + E[r][3]))
          + ((E[r][4] + E[r][5]) + (E[r][6] + E[r][7]));
  }
  #pragma unroll
  for (int r = 0; r < 8; r++) {
    #pragma unroll
    for (int o = 1; o < 64; o <<= 1) rp[r] += __shfl_xor(rp[r], o);
  }
  __shared__ float ws[8][8];   // [wave][row]
  __shared__ float eus[8];
  int w = t >> 6;
  if ((t & 63) == 0) {
    #pragma unroll
    for (int r = 0; r < 8; r++) ws[w][r] = rp[r];
  }
  __syncthreads();
  if (t < 8) {
    float S = 0.0f;
    #pragma unroll
    for (int ww = 0; ww < 8; ww++) S += ws[ww][t];
    S += __expf(vb[NN] - 30.0f);               // dustbin column term
    float ur = NORM_CONST - 30.0f - __logf(S);
    u[b * VST + r0 + t] = ur;
    eus[t] = __expf(ur);
  }
  __syncthreads();
  float eu[8];
  #pragma unroll
  for (int r = 0; r < 8; r++) eu[r] = eus[r];
  float outp[8];
  #pragma unroll
  for (int c = 0; c < 8; c++) {
    float acc = E[0][c] * eu[0];
    #pragma unroll
    for (int r = 1; r < 8; r++) acc = fmaf(E[r][c], eu[r], acc);
    outp[c] = acc * __expf(-50.5f - vmk[c]);   // * exp(-v_c)
  }
  float* pp = part + ((size_t)b * 512 + blk) * NN + c0;
  *(float4*)pp       = make_float4(outp[0], outp[1], outp[2], outp[3]);
  *(float4*)(pp + 4) = make_float4(outp[4], outp[5], outp[6], outp[7]);
}

// ---------------- 3b. stage2: reduce column partials -> v; dustbins ----------------
__launch_bounds__(256)
__global__ void sink_stage2(const float* __restrict__ part, const float* __restrict__ vin,
                            const float* __restrict__ u, float* __restrict__ vout) {
  int b = blockIdx.y, t = threadIdx.x;
  const float* vb = vin + b * VST;
  // u_dust = LOG_DUST - 30 - log( sum_c exp(v_c-30) + exp(v_dust-30) )
  float sv = 0.0f;
  #pragma unroll
  for (int i = 0; i < 16; i++) sv += __expf(vb[t + (i << 8)] - 30.0f);
  #pragma unroll
  for (int o = 1; o < 64; o <<= 1) sv += __shfl_xor(sv, o);
  __shared__ float sa[4];
  if ((t & 63) == 0) sa[t >> 6] = sv;
  __syncthreads();
  float S_v = sa[0] + sa[1] + sa[2] + sa[3] + __expf(vb[NN] - 30.0f);
  float eud = __expf(LOG_DUST - 60.0f - __logf(S_v));  // exp(u_dust - 30)

  int c = t & 31, h = t >> 5;
  int col = blockIdx.x * 32 + c;
  const float* pb = part + (size_t)b * 512 * NN + col;
  float acc = 0.0f;
  #pragma unroll 4
  for (int j = 0; j < 64; j++) acc += pb[(size_t)(h * 64 + j) * NN];
  __shared__ float red[256];
  red[t] = acc;
  __syncthreads();
  if (h == 0) {
    #pragma unroll
    for (int g = 1; g < 8; g++) acc += red[g * 32 + c];
    vout[b * VST + col] = NORM_CONST - 30.0f - __logf(acc + eud);
  }
  if (blockIdx.x == 0) {
    const float* ub = u + b * VST;
    float su = 0.0f;
    #pragma unroll
    for (int i = 0; i < 16; i++) su += __expf(ub[t + (i << 8)] - 30.0f);
    #pragma unroll
    for (int o = 1; o < 64; o <<= 1) su += __shfl_xor(su, o);
    __shared__ float sb[4];
    if ((t & 63) == 0) sb[t >> 6] = su;
    __syncthreads();
    if (t == 0)
      vout[b * VST + NN] = LOG_DUST - 30.0f - __logf(sb[0] + sb[1] + sb[2] + sb[3] + eud);
  }
}

// ---------------- 4. finalize: top-8 via u64 keys (exact ordering), entropy ----------------
// R5: branchless sorted-groups selection. Each lane pre-sorts its 4 groups of 4 keys
// (5-CE network, pure ILP). Per round: global max = max of 4 group heads (3 u64-max),
// butterfly, then a uniform shift-register pop in the winner's group. Keys are unique
// (index in low bits) -> emitted sequence identical to the flat 16-key scan.
__launch_bounds__(256)
__global__ void finalize_rows(const float* __restrict__ sim, const float* __restrict__ u,
                              const float* __restrict__ v, float* __restrict__ tkv,
                              int* __restrict__ tki, float* __restrict__ ent) {
  int m = blockIdx.x, b = blockIdx.y, t = threadIdx.x;
  const float4* srow = (const float4*)(sim + ((size_t)b * NN + m) * NN);
  const float4* v4 = (const float4*)(v + b * VST);
  float um = u[b * VST + m];
  unsigned long long key[16];
  float T1 = 0.0f, T2 = 0.0f;
  #pragma unroll
  for (int i = 0; i < 4; i++) {
    int idx = t + (i << 8);
    float4 s = srow[idx], vv = v4[idx];
    unsigned n0 = 4u * (unsigned)idx;
    float z, e;
    unsigned zb, k;
    z = fmaf(s.x, INV_TEMP, vv.x + um); e = __expf(z); T1 += e; T2 = fmaf(e, z, T2);
    zb = __float_as_uint(z); k = (zb & 0x80000000u) ? ~zb : (zb | 0x80000000u);
    key[4 * i + 0] = ((unsigned long long)k << 32) | (unsigned)(~n0);
    z = fmaf(s.y, INV_TEMP, vv.y + um); e = __expf(z); T1 += e; T2 = fmaf(e, z, T2);
    zb = __float_as_uint(z); k = (zb & 0x80000000u) ? ~zb : (zb | 0x80000000u);
    key[4 * i + 1] = ((unsigned long long)k << 32) | (unsigned)(~(n0 + 1));
    z = fmaf(s.z, INV_TEMP, vv.z + um); e = __expf(z); T1 += e; T2 = fmaf(e, z, T2);
    zb = __float_as_uint(z); k = (zb & 0x80000000u) ? ~zb : (zb | 0x80000000u);
    key[4 * i + 2] = ((unsigned long long)k << 32) | (unsigned)(~(n0 + 2));
    z = fmaf(s.w, INV_TEMP, vv.w + um); e = __expf(z); T1 += e; T2 = fmaf(e, z, T2);
    zb = __float_as_uint(z); k = (zb & 0x80000000u) ? ~zb : (zb | 0x80000000u);
    key[4 * i + 3] = ((unsigned long long)k << 32) | (unsigned)(~(n0 + 3));
  }
  #pragma unroll
  for (int o = 1; o < 64; o <<= 1) { T1 += __shfl_xor(T1, o); T2 += __shfl_xor(T2, o); }

  // pre-sort each group of 4 descending (sorting network [(0,1)(2,3)(0,2)(1,3)(1,2)])
  #pragma unroll
  for (int gi = 0; gi < 4; gi++) {
    unsigned long long k0 = key[4 * gi], k1 = key[4 * gi + 1];
    unsigned long long k2 = key[4 * gi + 2], k3 = key[4 * gi + 3];
    unsigned long long hi, lo;
    hi = k0 > k1 ? k0 : k1; lo = k0 > k1 ? k1 : k0; k0 = hi; k1 = lo;
    hi = k2 > k3 ? k2 : k3; lo = k2 > k3 ? k3 : k2; k2 = hi; k3 = lo;
    hi = k0 > k2 ? k0 : k2; lo = k0 > k2 ? k2 : k0; k0 = hi; k2 = lo;
    hi = k1 > k3 ? k1 : k3; lo = k1 > k3 ? k3 : k1; k1 = hi; k3 = lo;
    hi = k1 > k2 ? k1 : k2; lo = k1 > k2 ? k2 : k1; k1 = hi; k2 = lo;
    key[4 * gi] = k0; key[4 * gi + 1] = k1; key[4 * gi + 2] = k2; key[4 * gi + 3] = k3;
  }

  unsigned long long wv[8];
  #pragma unroll
  for (int r = 0; r < 8; r++) {
    unsigned long long m01 = key[0] > key[4] ? key[0] : key[4];
    unsigned long long m23 = key[8] > key[12] ? key[8] : key[12];
    unsigned long long mx = m01 > m23 ? m01 : m23;
    #pragma unroll
    for (int o = 1; o < 64; o <<= 1) {
      unsigned long long om = __shfl_xor(mx, o);
      mx = (om > mx) ? om : mx;
    }
    wv[r] = mx;
    // branchless pop: only the winner's group head can equal mx (keys unique)
    #pragma unroll
    for (int gi = 0; gi < 4; gi++) {
      bool c = (key[4 * gi] == mx);
      key[4 * gi]     = c ? key[4 * gi + 1] : key[4 * gi];
      key[4 * gi + 1] = c ? key[4 * gi + 2] : key[4 * gi + 1];
      key[4 * gi + 2] = c ? key[4 * gi + 3] : key[4 * gi + 2];
      key[4 * gi + 3] = c ? 0ull            : key[4 * gi + 3];
    }
  }

  __shared__ unsigned long long lv[4][8];
  __shared__ unsigned long long fv[8];
  __shared__ float sT1[4], sT2[4];
  int wid = t >> 6;
  if ((t & 63) == 0) {
    sT1[wid] = T1; sT2[wid] = T2;
    #pragma unroll
    for (int j = 0; j < 8; j++) lv[wid][j] = wv[j];
  }
  __syncthreads();
  if (t == 0) {
    int p[4] = {0, 0, 0, 0};
    for (int k2 = 0; k2 < 8; k2++) {
      unsigned long long best = 0ull; int bw = 0;
      #pragma unroll
      for (int w = 0; w < 4; w++) {
        if (p[w] < 8 && lv[w][p[w]] > best) { best = lv[w][p[w]]; bw = w; }
      }
      fv[k2] = best; p[bw]++;
    }
  }
  __syncthreads();
  size_t ro = ((size_t)b * NN + m) * NK;
  if (t < 8) {
    unsigned long long kk = fv[t];
    unsigned kh = (unsigned)(kk >> 32);
    unsigned zb = (kh & 0x80000000u) ? (kh & 0x7FFFFFFFu) : ~kh;
    tkv[ro + t] = __expf(__uint_as_float(zb));
    tki[ro + t] = (int)(~(unsigned)kk);
  }
  if (t == 0) {
    float T1t = sT1[0] + sT1[1] + sT1[2] + sT1[3];
    float T2t = sT2[0] + sT2[1] + sT2[2] + sT2[3];
    float denom = T1t + 1e-8f;
    float ld = __logf(denom);
    ent[b * NN + m] = (T1t * ld - T2t) / denom;
  }
}

// ---------------- 5. geometric score: banded 7x7 local variance ----------------
__launch_bounds__(256)
__global__ void geo_kernel(const int* __restrict__ tki, const float* __restrict__ posA,
                           const float* __restrict__ posB, float* __restrict__ geo) {
  int k = blockIdx.x, band = blockIdx.y, b = blockIdx.z, t = threadIdx.x;
  int r0 = band * 8, rlo = r0 - 3;
  __shared__ float s1[14 * 64], s2[14 * 64], h1[14 * 64], h2[14 * 64];
  const float* pA = posA + (size_t)b * NN * 2;
  const float* pB = posB + (size_t)b * NN * 2;
  const int* idx = tki + (size_t)b * NN * NK + k;
  for (int e = t; e < 14 * 64; e += 256) {
    int rr = rlo + (e >> 6), w = e & 63;
    float v1 = 0.0f, v2 = 0.0f;
    if (rr >= 0 && rr < 64) {
      int n = rr * 64 + w;
      int j = idx[(size_t)n * NK];
      float dx = pB[(size_t)j * 2]     - pA[(size_t)n * 2];
      float dy = pB[(size_t)j * 2 + 1] - pA[(size_t)n * 2 + 1];
      v1 = dx + dy;
      v2 = dx * dx + dy * dy;
    }
    s1[e] = v1; s2[e] = v2;
  }
  __syncthreads();
  for (int e = t; e < 14 * 64; e += 256) {
    int w = e & 63, base = e - w;
    float a1 = 0.0f, a2 = 0.0f;
    for (int dw = -3; dw <= 3; dw++) {
      int ww = w + dw;
      if (ww >= 0 && ww < 64) { a1 += s1[base + ww]; a2 += s2[base + ww]; }
    }
    h1[e] = a1; h2[e] = a2;
  }
  __syncthreads();
  for (int o = t; o < 8 * 64; o += 256) {
    int lr = (o >> 6) + 3, w = o & 63;
    int e = lr * 64 + w;
    float b1 = 0.0f, b2 = 0.0f;
    #pragma unroll
    for (int dh = -3; dh <= 3; dh++) { b1 += h1[e + dh * 64]; b2 += h2[e + dh * 64]; }
    float mean = b1 * (1.0f / 98.0f);
    float var = (b2 - b1 * mean) * (1.0f / 97.0f);
    int n = (r0 + (o >> 6)) * 64 + w;
    geo[((size_t)b * NN + n) * NK + k] = 1.0f / (1.0f + var * 100.0f);
  }
}

// ---------------- 6. combine: softmax over K, weighted warp ----------------
__launch_bounds__(256)
__global__ void combine_kernel(const float* __restrict__ tkv, const float* __restrict__ geo,
                               const int* __restrict__ tki, const float* __restrict__ posB,
                               float* __restrict__ warp) {
  int id = blockIdx.x * 256 + threadIdx.x;
  int b = id / NN;
  const float* vals = tkv + (size_t)id * NK;
  const float* g    = geo + (size_t)id * NK;
  const int*   ix   = tki + (size_t)id * NK;
  const float* pB   = posB + (size_t)b * NN * 2;
  float l[8], mx = -3.0e38f;
  #pragma unroll
  for (int j = 0; j < 8; j++) {
    l[j] = (vals[j] + 1.5f * g[j]) * INV_TEMP;
    mx = fmaxf(mx, l[j]);
  }
  float sw = 0.0f, wx = 0.0f, wy = 0.0f;
  #pragma unroll
  for (int j = 0; j < 8; j++) {
    float w = __expf(l[j] - mx);
    int jj = ix[j];
    sw += w;
    wx = fmaf(w, pB[(size_t)jj * 2], wx);
    wy = fmaf(w, pB[(size_t)jj * 2 + 1], wy);
  }
  warp[(size_t)id * 2]     = wx / sw;
  warp[(size_t)id * 2 + 1] = wy / sw;
}

extern "C" void kernel_launch(void* const* d_in, const int* in_sizes, int n_in,
                              void* d_out, int out_size, void* d_ws, size_t ws_size,
                              hipStream_t stream) {
  const float* fA = (const float*)d_in[0];
  const float* fB = (const float*)d_in[1];
  const float* pA = (const float*)d_in[2];
  const float* pB = (const float*)d_in[3];

  float* out  = (float*)d_out;
  float* warp = out;                       // [B,N,2]
  float* ent  = out + (size_t)NB * NN * 2; // [B,N]
  float* sim  = ent + (size_t)NB * NN;     // [B,N,N] raw_sim (also Sinkhorn cost)

  size_t off = 0;
  auto take = [&](size_t bytes) {
    void* p = (char*)d_ws + off;
    off = (off + bytes + 255) & ~(size_t)255;
    return p;
  };
  __hip_bfloat16* Ah = (__hip_bfloat16*)take((size_t)NB * NN * NC * 2);
  __hip_bfloat16* Al = (__hip_bfloat16*)take((size_t)NB * NN * NC * 2);
  __hip_bfloat16* Bh = (__hip_bfloat16*)take((size_t)NB * NN * NC * 2);
  __hip_bfloat16* Bl = (__hip_bfloat16*)take((size_t)NB * NN * NC * 2);
  float* uu   = (float*)take((size_t)NB * VST * 4);
  float* v0   = (float*)take((size_t)NB * VST * 4);
  float* v1   = (float*)take((size_t)NB * VST * 4);
  float* part = (float*)take((size_t)NB * 512 * NN * 4);
  unsigned short* s16 = (unsigned short*)take((size_t)NB * NN * NN * 2);
  float* tkv  = (float*)take((size_t)NB * NN * NK * 4);
  int*   tki  = (int*)take((size_t)NB * NN * NK * 4);
  float* geo  = (float*)take((size_t)NB * NN * NK * 4);
  (void)off; (void)ws_size;

  norm_split<<<dim3(2 * NB * NN), 64, 0, stream>>>(fA, fB, Ah, Al, Bh, Bl, v0);
  gemm_mfma<<<dim3(NN / 128, NN / 128, NB), 256, 0, stream>>>(Ah, Al, Bh, Bl, sim, s16);
  for (int it = 0; it < 5; it++) {
    float* vin  = (it & 1) ? v1 : v0;
    float* vout = (it & 1) ? v0 : v1;
    sink_fused<<<dim3(NN / 8, NB), 512, 0, stream>>>(s16, vin, uu, part);
    sink_stage2<<<dim3(128, NB), 256, 0, stream>>>(part, vin, uu, vout);
  }
  finalize_rows<<<dim3(NN, NB), 256, 0, stream>>>(sim, uu, v1, tkv, tki, ent);
  geo_kernel<<<dim3(NK, 8, NB), 256, 0, stream>>>(tki, pA, pB, geo);
  combine_kernel<<<dim3((NB * NN) / 256), 256, 0, stream>>>(tkv, geo, tki, pB, warp);
}